// Round 14
// baseline (701.212 us; speedup 1.0000x reference)
//
#include <hip/hip_runtime.h>

#define DEV_INLINE __device__ __forceinline__

typedef __attribute__((ext_vector_type(8))) short bf16x8;
typedef __attribute__((ext_vector_type(4))) float f32x4;

// ---------- bf16 bit helpers ----------
DEV_INLINE unsigned short f2bf(float f) {
  union { float f; unsigned u; } v; v.f = f;
  unsigned r = v.u + 0x7FFFu + ((v.u >> 16) & 1u);  // round-to-nearest-even
  return (unsigned short)(r >> 16);
}
DEV_INLINE float bf2f(unsigned short u) {
  union { unsigned u; float f; } v; v.u = ((unsigned)u) << 16;
  return v.f;
}
DEV_INLINE float sigmoidf_(float x) { return 1.0f / (1.0f + __expf(-x)); }

DEV_INLINE void gload_lds16(const void* g, void* l) {
  __builtin_amdgcn_global_load_lds(
      (const __attribute__((address_space(1))) void*)(g),
      (__attribute__((address_space(3))) void*)(l), 16, 0, 0);
}

// ---------- fused prep: x fp32->bf16 (blocks 0..8191) + 4 weight transposes ----------
__global__ __launch_bounds__(256)
void prep_kernel(const float* __restrict__ x, unsigned short* __restrict__ xbf,
                 const float* __restrict__ W0, unsigned short* __restrict__ Wt0,
                 const float* __restrict__ W1, unsigned short* __restrict__ Wt1,
                 const float* __restrict__ W2, unsigned short* __restrict__ Wt2,
                 const float* __restrict__ W3, unsigned short* __restrict__ Wt3) {
  __shared__ float tile[32][33];
  const int id = blockIdx.x;
  const int t = threadIdx.x;
  if (id < 8192) {                      // x convert: 8192*256 float4 = 32768*256 floats
    const int i = id * 256 + t;
    const float4 v = reinterpret_cast<const float4*>(x)[i];
    ushort4 o;
    o.x = f2bf(v.x); o.y = f2bf(v.y); o.z = f2bf(v.z); o.w = f2bf(v.w);
    reinterpret_cast<ushort4*>(xbf)[i] = o;
    return;
  }
  int rid = id - 8192;
  const float* W; unsigned short* Wt; int K, N, bx, by;
  if (rid < 512) {                      // W0: [256][2048] -> [2048][256]
    W = W0; Wt = Wt0; K = 256; N = 2048; bx = rid & 7; by = rid >> 3;
  } else {                              // W1..W3: [512][1536] -> [1536][512]
    rid -= 512;
    const int seg = rid / 768; rid -= seg * 768;
    K = 512; N = 1536;
    W  = seg == 0 ? W1  : (seg == 1 ? W2  : W3);
    Wt = seg == 0 ? Wt1 : (seg == 1 ? Wt2 : Wt3);
    bx = rid & 15; by = rid >> 4;
  }
  const int tx = t & 31, ty = t >> 5;   // (32,8)
  const int kb = bx * 32, nb = by * 32;
  #pragma unroll
  for (int i = 0; i < 32; i += 8)
    tile[ty + i][tx] = W[(size_t)(kb + ty + i) * N + (nb + tx)];
  __syncthreads();
  #pragma unroll
  for (int i = 0; i < 32; i += 8)
    Wt[(size_t)(nb + ty + i) * K + (kb + tx)] = f2bf(tile[tx][ty + i]);
}

// ---------- GEMM + fused gate epilogue (R12-validated optimum) ----------
// Block tile 128(M) x 128(N), BK=64, 512 thr = 8 waves as 2M x 4N
// (wave-tile 64x32). Single-buffer: stage -> barrier -> compute -> barrier.
// LDS 32 KiB (A 16 + B 16).
// U[m][n] = gate_n( sum_k A[m][k]*Bt[n][k] )  stored bf16.
// regions (H=512): n>>9==1 -> sigmoid(v+bias[n&511]); ==2 -> sigmoid(v+bias[512+(n&511)]).
__global__ __launch_bounds__(512, 4)
void gemm_gate_kernel(const unsigned short* __restrict__ A,   // [M][K] bf16 bits
                      const unsigned short* __restrict__ Bt,  // [N][K] bf16 bits
                      const float* __restrict__ bias,         // [1024]
                      unsigned short* __restrict__ U,         // [M][N] bf16 bits
                      int N, int K, int NTN) {
  __shared__ short smem[2 * 128 * 64];   // As 16 KiB | Bs 16 KiB
  short* As = smem;
  short* Bs = smem + 128 * 64;

  const int tid = threadIdx.x;
  const int lane = tid & 63;
  const int l15 = lane & 15;
  const int l4 = lane >> 4;
  const int w = tid >> 6;          // 0..7
  const int wr = (w >> 2) * 64;    // wave M offset (0 or 64)
  const int wc = (w & 3) * 32;     // wave N offset (0,32,64,96)

  // XCD-aware bijective swizzle, then ntile-fast decomposition for L2 reuse.
  const int nwg = gridDim.x;            // multiple of 8
  const int cpx = nwg >> 3;
  const int swz = (blockIdx.x & 7) * cpx + (blockIdx.x >> 3);
  const int mtile = swz / NTN;
  const int ntile = swz - mtile * NTN;
  const int m0 = mtile * 128;
  const int n0 = ntile * 128;

  f32x4 acc[4][2];
  #pragma unroll
  for (int i = 0; i < 4; ++i)
    #pragma unroll
    for (int j = 0; j < 2; ++j)
      acc[i][j] = (f32x4){0.f, 0.f, 0.f, 0.f};

  const unsigned short* Abase = A + (size_t)m0 * K;
  const unsigned short* Bbase = Bt + (size_t)n0 * K;
  const int nsteps = K >> 6;

  for (int t = 0; t < nsteps; ++t) {
    const int k0 = t * 64;
    // stage A tile [128][64] and B tile [128][64], 2 chunks/thread each;
    // linear LDS dest, source k-slot pre-swizzled (involution sl ^ (row&7)).
    #pragma unroll
    for (int it = 0; it < 2; ++it) {
      int c = it * 512 + tid;
      int row = c >> 3, sl = c & 7;
      int ks = sl ^ (row & 7);
      gload_lds16(Abase + (size_t)row * K + (k0 + ks * 8), &As[c * 8]);
    }
    #pragma unroll
    for (int it = 0; it < 2; ++it) {
      int c = it * 512 + tid;
      int row = c >> 3, sl = c & 7;
      int ks = sl ^ (row & 7);
      gload_lds16(Bbase + (size_t)row * K + (k0 + ks * 8), &Bs[c * 8]);
    }
    __syncthreads();

    const bf16x8* As8 = (const bf16x8*)As;
    const bf16x8* Bs8 = (const bf16x8*)Bs;
    #pragma unroll
    for (int kk = 0; kk < 2; ++kk) {
      bf16x8 af[4], bfr[2];
      #pragma unroll
      for (int i = 0; i < 4; ++i) {
        int r = wr + i * 16 + l15;
        int phys = (kk * 4 + l4) ^ (r & 7);
        af[i] = As8[r * 8 + phys];
      }
      #pragma unroll
      for (int j = 0; j < 2; ++j) {
        int r = wc + j * 16 + l15;
        int phys = (kk * 4 + l4) ^ (r & 7);
        bfr[j] = Bs8[r * 8 + phys];
      }
      #pragma unroll
      for (int i = 0; i < 4; ++i)
        #pragma unroll
        for (int j = 0; j < 2; ++j)
          acc[i][j] = __builtin_amdgcn_mfma_f32_16x16x32_bf16(af[i], bfr[j], acc[i][j], 0, 0, 0);
    }
    __syncthreads();
  }

  // ---- epilogue: gate + direct bf16 stores (validated pattern) ----
  #pragma unroll
  for (int i = 0; i < 4; ++i) {
    const int grow0 = m0 + wr + i * 16 + l4 * 4;
    #pragma unroll
    for (int j = 0; j < 2; ++j) {
      const int gcol = n0 + wc + j * 16 + l15;
      const int region = gcol >> 9;
      const bool gate = (region == 1) | (region == 2);
      const float bval = (region == 1) ? bias[gcol & 511]
                       : ((region == 2) ? bias[512 + (gcol & 511)] : 0.f);
      #pragma unroll
      for (int reg = 0; reg < 4; ++reg) {
        float v = acc[i][j][reg];
        if (gate) v = sigmoidf_(v + bval);
        U[(size_t)(grow0 + reg) * N + gcol] = f2bf(v);
      }
    }
  }
}

// ---------- chunked linear-recurrence scan, register-cached xt/f ----------
// grid: 32 b x 8 hslices = 256 blocks; block: 512 thr = 64 chunks(16 steps) x 8 hv.
// Pass 1 loads xt,f ONCE into registers (fully unrolled -> static indexing,
// rule #20); pass 2 reuses them, reading only r (+xres) and writing h.
// Saves 67 MB of re-read traffic per layer vs the 2-read version.
__global__ __launch_bounds__(512)
void scan_kernel(const unsigned short* __restrict__ U, int N, int first,
                 const unsigned short* __restrict__ hin,   // [M][512] bf16 (xres) if !first
                 unsigned short* __restrict__ hout_bf,     // [M][512] bf16 or null
                 float* __restrict__ hout_f32,             // [M][512] f32 or null
                 float* __restrict__ hidden) {             // [B][512]
  const int b = blockIdx.x >> 3;
  const int hslice = blockIdx.x & 7;
  const int hv = threadIdx.x & 7;
  const int ch = threadIdx.x >> 3;
  const int h0 = (hslice << 6) + (hv << 3);
  __shared__ float sP[64 * 68];
  __shared__ float sQ[64 * 68];

  const size_t rowBase = (size_t)b * 1024 + (size_t)ch * 16;
  const unsigned short* Uxt = U + rowBase * N + h0;

  // pass 1: chunk-local (P, Q) with c_in = 0; cache xt,f in registers
  bf16x8 xc[16], fc[16];
  float c[8], P[8];
  #pragma unroll
  for (int j = 0; j < 8; ++j) { c[j] = 0.f; P[j] = 1.f; }
  {
    const unsigned short* px = Uxt;
    const unsigned short* pf = Uxt + 512;
    #pragma unroll
    for (int l = 0; l < 16; ++l) {
      xc[l] = *(const bf16x8*)px;
      fc[l] = *(const bf16x8*)pf;
      #pragma unroll
      for (int j = 0; j < 8; ++j) {
        float f  = bf2f((unsigned short)fc[l][j]);
        float xt = bf2f((unsigned short)xc[l][j]);
        c[j] = f * c[j] + (1.f - f) * xt;
        P[j] *= f;
      }
      px += N; pf += N;
    }
  }
  float* myP = &sP[ch * 68 + hv * 8];
  float* myQ = &sQ[ch * 68 + hv * 8];
  #pragma unroll
  for (int j = 0; j < 8; ++j) { myP[j] = P[j]; myQ[j] = c[j]; }
  __syncthreads();

  // Hillis-Steele inclusive affine scan over chunks.
  // Race-hardened: unconditional clamped-index read, then explicit lgkmcnt(0)
  // pin (+sched_barrier, rule #18) so reads provably complete before the
  // barrier that releases the partner's overwrite.
  for (int s = 1; s < 64; s <<= 1) {
    const int src = (ch >= s) ? (ch - s) : ch;
    float pp[8], pq[8];
    const float* qP = &sP[src * 68 + hv * 8];
    const float* qQ = &sQ[src * 68 + hv * 8];
    #pragma unroll
    for (int j = 0; j < 8; ++j) { pp[j] = qP[j]; pq[j] = qQ[j]; }
    asm volatile("s_waitcnt lgkmcnt(0)" ::: "memory");
    __builtin_amdgcn_sched_barrier(0);
    __syncthreads();
    if (ch >= s) {
      #pragma unroll
      for (int j = 0; j < 8; ++j) {
        c[j] = P[j] * pq[j] + c[j];
        P[j] = P[j] * pp[j];
        myP[j] = P[j]; myQ[j] = c[j];
      }
    }
    __syncthreads();
  }

  float cc[8];
  if (ch == 0) {
    #pragma unroll
    for (int j = 0; j < 8; ++j) cc[j] = 0.f;
  } else {
    const float* qQ = &sQ[(ch - 1) * 68 + hv * 8];
    #pragma unroll
    for (int j = 0; j < 8; ++j) cc[j] = qQ[j];
  }

  // pass 2: real scan + highway write (xt,f from registers)
  const unsigned short* pr = Uxt + 1024;
  const unsigned short* pxr = first ? (Uxt + 1536) : (hin + rowBase * 512 + h0);
  const int xr_stride = first ? N : 512;
  unsigned short* ob = hout_bf ? hout_bf + rowBase * 512 + h0 : (unsigned short*)nullptr;
  float* of = hout_f32 ? hout_f32 + rowBase * 512 + h0 : (float*)nullptr;
  #pragma unroll
  for (int l = 0; l < 16; ++l) {
    bf16x8 rv = *(const bf16x8*)pr;
    bf16x8 xrv = *(const bf16x8*)pxr;
    bf16x8 obuf;
    float ofl[8];
    #pragma unroll
    for (int j = 0; j < 8; ++j) {
      float f  = bf2f((unsigned short)fc[l][j]);
      float xt = bf2f((unsigned short)xc[l][j]);
      cc[j] = f * cc[j] + (1.f - f) * xt;
      float r  = bf2f((unsigned short)rv[j]);
      float xr = bf2f((unsigned short)xrv[j]);
      float o = r * cc[j] + (1.f - r) * xr;
      obuf[j] = (short)f2bf(o);
      ofl[j] = o;
    }
    if (ob) { *(bf16x8*)ob = obuf; ob += 512; }
    if (of) {
      *(float4*)of = make_float4(ofl[0], ofl[1], ofl[2], ofl[3]);
      *(float4*)(of + 4) = make_float4(ofl[4], ofl[5], ofl[6], ofl[7]);
      of += 512;
    }
    pr += N; pxr += xr_stride;
  }
  if (ch == 63) {
    #pragma unroll
    for (int j = 0; j < 8; ++j) hidden[(size_t)b * 512 + h0 + j] = cc[j];
  }
}

// ---------- head ----------
__global__ __launch_bounds__(256)
void proj_kernel(const float* __restrict__ hfull, const float* __restrict__ Wp,
                 const float* __restrict__ bp, const float* __restrict__ Wc,
                 const float* __restrict__ bc, float* __restrict__ out) {
  __shared__ float hl[512];
  __shared__ float pr[512];
  const int b = blockIdx.x, t = threadIdx.x;
  const float* hrow = hfull + ((size_t)b * 1024 + 1023) * 512;
  hl[t] = hrow[t];
  hl[t + 256] = hrow[t + 256];
  __syncthreads();
  for (int j = t; j < 512; j += 256) {
    float s = 0.f;
    for (int k = 0; k < 512; ++k) s += hl[k] * Wp[(size_t)k * 512 + j];
    pr[j] = s + bp[j];
  }
  __syncthreads();
  if (t < 16) {
    float s = 0.f;
    for (int k = 0; k < 512; ++k) s += pr[k] * Wc[k * 16 + t];
    out[b * 16 + t] = s + bc[t];
  }
}

extern "C" void kernel_launch(void* const* d_in, const int* in_sizes, int n_in,
                              void* d_out, int out_size, void* d_ws, size_t ws_size,
                              hipStream_t stream) {
  const float* x  = (const float*)d_in[0];
  const float* W0 = (const float*)d_in[1];
  const float* b0 = (const float*)d_in[2];
  const float* W1 = (const float*)d_in[3];
  const float* b1 = (const float*)d_in[4];
  const float* W2 = (const float*)d_in[5];
  const float* b2 = (const float*)d_in[6];
  const float* W3 = (const float*)d_in[7];
  const float* b3 = (const float*)d_in[8];
  const float* Wp = (const float*)d_in[9];
  const float* bp = (const float*)d_in[10];
  const float* Wc = (const float*)d_in[11];
  const float* bc = (const float*)d_in[12];

  float* out = (float*)d_out;
  float* outO = out;                                   // (32,16)
  float* outH = out + 512;                             // (32,1024,512)
  float* outHid = out + 512 + (size_t)32 * 1024 * 512; // (4,32,512)

  char* ws = (char*)d_ws;
  size_t off = 0;
  auto alloc = [&](size_t bytes) {
    void* p = ws + off;
    off += (bytes + 255) & ~(size_t)255;
    return p;
  };
  unsigned short* Wt0 = (unsigned short*)alloc((size_t)2048 * 256 * 2);
  unsigned short* Wt1 = (unsigned short*)alloc((size_t)1536 * 512 * 2);
  unsigned short* Wt2 = (unsigned short*)alloc((size_t)1536 * 512 * 2);
  unsigned short* Wt3 = (unsigned short*)alloc((size_t)1536 * 512 * 2);
  unsigned short* xbf = (unsigned short*)alloc((size_t)32768 * 256 * 2);
  unsigned short* h0  = (unsigned short*)alloc((size_t)32768 * 512 * 2);
  unsigned short* h1  = (unsigned short*)alloc((size_t)32768 * 512 * 2);
  unsigned short* Ubf = (unsigned short*)alloc((size_t)32768 * 2048 * 2);
  (void)ws_size; (void)in_sizes; (void)n_in; (void)out_size;

  // fused prep: 8192 convert blocks + 512 + 3*768 transpose blocks
  prep_kernel<<<8192 + 512 + 3 * 768, 256, 0, stream>>>(
      x, xbf, W0, Wt0, W1, Wt1, W2, Wt2, W3, Wt3);

  // layer 0: K=256, N=2048 (xt | f | r | xres); 256 mtiles x 16 ntiles
  gemm_gate_kernel<<<256 * 16, 512, 0, stream>>>(xbf, Wt0, b0, Ubf, 2048, 256, 16);
  scan_kernel<<<256, 512, 0, stream>>>(Ubf, 2048, 1, nullptr, h0, nullptr, outHid + 0);
  // layer 1: 256 x 12
  gemm_gate_kernel<<<256 * 12, 512, 0, stream>>>(h0, Wt1, b1, Ubf, 1536, 512, 12);
  scan_kernel<<<256, 512, 0, stream>>>(Ubf, 1536, 0, h0, h1, nullptr, outHid + 16384);
  // layer 2
  gemm_gate_kernel<<<256 * 12, 512, 0, stream>>>(h1, Wt2, b2, Ubf, 1536, 512, 12);
  scan_kernel<<<256, 512, 0, stream>>>(Ubf, 1536, 0, h1, h0, nullptr, outHid + 32768);
  // layer 3: write final h as fp32 straight to d_out
  gemm_gate_kernel<<<256 * 12, 512, 0, stream>>>(h0, Wt3, b3, Ubf, 1536, 512, 12);
  scan_kernel<<<256, 512, 0, stream>>>(Ubf, 1536, 0, h0, nullptr, outH, outHid + 49152);

  proj_kernel<<<32, 256, 0, stream>>>(outH, Wp, bp, Wc, bc, outO);
}

// Round 15
// 542.688 us; speedup vs baseline: 1.2921x; 1.2921x over previous
//
#include <hip/hip_runtime.h>

#define DEV_INLINE __device__ __forceinline__

typedef __attribute__((ext_vector_type(8))) short bf16x8;
typedef __attribute__((ext_vector_type(4))) short bf16x4;
typedef __attribute__((ext_vector_type(4))) float f32x4;

// ---------- bf16 bit helpers ----------
DEV_INLINE unsigned short f2bf(float f) {
  union { float f; unsigned u; } v; v.f = f;
  unsigned r = v.u + 0x7FFFu + ((v.u >> 16) & 1u);  // round-to-nearest-even
  return (unsigned short)(r >> 16);
}
DEV_INLINE float bf2f(unsigned short u) {
  union { unsigned u; float f; } v; v.u = ((unsigned)u) << 16;
  return v.f;
}
DEV_INLINE float sigmoidf_(float x) { return 1.0f / (1.0f + __expf(-x)); }

DEV_INLINE void gload_lds16(const void* g, void* l) {
  __builtin_amdgcn_global_load_lds(
      (const __attribute__((address_space(1))) void*)(g),
      (__attribute__((address_space(3))) void*)(l), 16, 0, 0);
}

// ---------- fused prep: x fp32->bf16 (blocks 0..8191) + 4 weight transposes ----------
__global__ __launch_bounds__(256)
void prep_kernel(const float* __restrict__ x, unsigned short* __restrict__ xbf,
                 const float* __restrict__ W0, unsigned short* __restrict__ Wt0,
                 const float* __restrict__ W1, unsigned short* __restrict__ Wt1,
                 const float* __restrict__ W2, unsigned short* __restrict__ Wt2,
                 const float* __restrict__ W3, unsigned short* __restrict__ Wt3) {
  __shared__ float tile[32][33];
  const int id = blockIdx.x;
  const int t = threadIdx.x;
  if (id < 8192) {                      // x convert: 8192*256 float4 = 32768*256 floats
    const int i = id * 256 + t;
    const float4 v = reinterpret_cast<const float4*>(x)[i];
    ushort4 o;
    o.x = f2bf(v.x); o.y = f2bf(v.y); o.z = f2bf(v.z); o.w = f2bf(v.w);
    reinterpret_cast<ushort4*>(xbf)[i] = o;
    return;
  }
  int rid = id - 8192;
  const float* W; unsigned short* Wt; int K, N, bx, by;
  if (rid < 512) {                      // W0: [256][2048] -> [2048][256]
    W = W0; Wt = Wt0; K = 256; N = 2048; bx = rid & 7; by = rid >> 3;
  } else {                              // W1..W3: [512][1536] -> [1536][512]
    rid -= 512;
    const int seg = rid / 768; rid -= seg * 768;
    K = 512; N = 1536;
    W  = seg == 0 ? W1  : (seg == 1 ? W2  : W3);
    Wt = seg == 0 ? Wt1 : (seg == 1 ? Wt2 : Wt3);
    bx = rid & 15; by = rid >> 4;
  }
  const int tx = t & 31, ty = t >> 5;   // (32,8)
  const int kb = bx * 32, nb = by * 32;
  #pragma unroll
  for (int i = 0; i < 32; i += 8)
    tile[ty + i][tx] = W[(size_t)(kb + ty + i) * N + (nb + tx)];
  __syncthreads();
  #pragma unroll
  for (int i = 0; i < 32; i += 8)
    Wt[(size_t)(nb + ty + i) * K + (kb + tx)] = f2bf(tile[tx][ty + i]);
}

// ---------- GEMM + fused gate epilogue (R12-validated optimum) ----------
// Block tile 128(M) x 128(N), BK=64, 512 thr = 8 waves as 2M x 4N
// (wave-tile 64x32). Single-buffer: stage -> barrier -> compute -> barrier.
// LDS 32 KiB (A 16 + B 16).
// U[m][n] = gate_n( sum_k A[m][k]*Bt[n][k] )  stored bf16.
// regions (H=512): n>>9==1 -> sigmoid(v+bias[n&511]); ==2 -> sigmoid(v+bias[512+(n&511)]).
__global__ __launch_bounds__(512, 4)
void gemm_gate_kernel(const unsigned short* __restrict__ A,   // [M][K] bf16 bits
                      const unsigned short* __restrict__ Bt,  // [N][K] bf16 bits
                      const float* __restrict__ bias,         // [1024]
                      unsigned short* __restrict__ U,         // [M][N] bf16 bits
                      int N, int K, int NTN) {
  __shared__ short smem[2 * 128 * 64];   // As 16 KiB | Bs 16 KiB
  short* As = smem;
  short* Bs = smem + 128 * 64;

  const int tid = threadIdx.x;
  const int lane = tid & 63;
  const int l15 = lane & 15;
  const int l4 = lane >> 4;
  const int w = tid >> 6;          // 0..7
  const int wr = (w >> 2) * 64;    // wave M offset (0 or 64)
  const int wc = (w & 3) * 32;     // wave N offset (0,32,64,96)

  // XCD-aware bijective swizzle, then ntile-fast decomposition for L2 reuse.
  const int nwg = gridDim.x;            // multiple of 8
  const int cpx = nwg >> 3;
  const int swz = (blockIdx.x & 7) * cpx + (blockIdx.x >> 3);
  const int mtile = swz / NTN;
  const int ntile = swz - mtile * NTN;
  const int m0 = mtile * 128;
  const int n0 = ntile * 128;

  f32x4 acc[4][2];
  #pragma unroll
  for (int i = 0; i < 4; ++i)
    #pragma unroll
    for (int j = 0; j < 2; ++j)
      acc[i][j] = (f32x4){0.f, 0.f, 0.f, 0.f};

  const unsigned short* Abase = A + (size_t)m0 * K;
  const unsigned short* Bbase = Bt + (size_t)n0 * K;
  const int nsteps = K >> 6;

  for (int t = 0; t < nsteps; ++t) {
    const int k0 = t * 64;
    // stage A tile [128][64] and B tile [128][64], 2 chunks/thread each;
    // linear LDS dest, source k-slot pre-swizzled (involution sl ^ (row&7)).
    #pragma unroll
    for (int it = 0; it < 2; ++it) {
      int c = it * 512 + tid;
      int row = c >> 3, sl = c & 7;
      int ks = sl ^ (row & 7);
      gload_lds16(Abase + (size_t)row * K + (k0 + ks * 8), &As[c * 8]);
    }
    #pragma unroll
    for (int it = 0; it < 2; ++it) {
      int c = it * 512 + tid;
      int row = c >> 3, sl = c & 7;
      int ks = sl ^ (row & 7);
      gload_lds16(Bbase + (size_t)row * K + (k0 + ks * 8), &Bs[c * 8]);
    }
    __syncthreads();

    const bf16x8* As8 = (const bf16x8*)As;
    const bf16x8* Bs8 = (const bf16x8*)Bs;
    #pragma unroll
    for (int kk = 0; kk < 2; ++kk) {
      bf16x8 af[4], bfr[2];
      #pragma unroll
      for (int i = 0; i < 4; ++i) {
        int r = wr + i * 16 + l15;
        int phys = (kk * 4 + l4) ^ (r & 7);
        af[i] = As8[r * 8 + phys];
      }
      #pragma unroll
      for (int j = 0; j < 2; ++j) {
        int r = wc + j * 16 + l15;
        int phys = (kk * 4 + l4) ^ (r & 7);
        bfr[j] = Bs8[r * 8 + phys];
      }
      #pragma unroll
      for (int i = 0; i < 4; ++i)
        #pragma unroll
        for (int j = 0; j < 2; ++j)
          acc[i][j] = __builtin_amdgcn_mfma_f32_16x16x32_bf16(af[i], bfr[j], acc[i][j], 0, 0, 0);
    }
    __syncthreads();
  }

  // ---- epilogue: gate + direct bf16 stores (validated pattern) ----
  #pragma unroll
  for (int i = 0; i < 4; ++i) {
    const int grow0 = m0 + wr + i * 16 + l4 * 4;
    #pragma unroll
    for (int j = 0; j < 2; ++j) {
      const int gcol = n0 + wc + j * 16 + l15;
      const int region = gcol >> 9;
      const bool gate = (region == 1) | (region == 2);
      const float bval = (region == 1) ? bias[gcol & 511]
                       : ((region == 2) ? bias[512 + (gcol & 511)] : 0.f);
      #pragma unroll
      for (int reg = 0; reg < 4; ++reg) {
        float v = acc[i][j][reg];
        if (gate) v = sigmoidf_(v + bval);
        U[(size_t)(grow0 + reg) * N + gcol] = f2bf(v);
      }
    }
  }
}

// ---------- chunked linear-recurrence scan, register-cached xt/f (4 h/thread) ----------
// grid: 32 b x 16 hslices = 512 blocks; block: 512 thr = 64 chunks(16 steps) x 8 hv
// of 4 h each. Cache = 16 x bf16x4 x 2 = 64 VGPRs (fits, no spill -- R14's
// 8-h version needed 128 for cache alone and spilled).
// Pass 2 reuses cached xt,f: reads only r (+xres), writes h.
__global__ __launch_bounds__(512)
void scan_kernel(const unsigned short* __restrict__ U, int N, int first,
                 const unsigned short* __restrict__ hin,   // [M][512] bf16 (xres) if !first
                 unsigned short* __restrict__ hout_bf,     // [M][512] bf16 or null
                 float* __restrict__ hout_f32,             // [M][512] f32 or null
                 float* __restrict__ hidden) {             // [B][512]
  const int b = blockIdx.x >> 4;
  const int hslice = blockIdx.x & 15;
  const int hv = threadIdx.x & 7;
  const int ch = threadIdx.x >> 3;
  const int h0 = (hslice << 5) + (hv << 2);
  __shared__ float sP[64 * 36];
  __shared__ float sQ[64 * 36];

  const size_t rowBase = (size_t)b * 1024 + (size_t)ch * 16;
  const unsigned short* Uxt = U + rowBase * N + h0;

  // pass 1: chunk-local (P, Q) with c_in = 0; cache xt,f in registers
  bf16x4 xc[16], fc[16];
  float c[4], P[4];
  #pragma unroll
  for (int j = 0; j < 4; ++j) { c[j] = 0.f; P[j] = 1.f; }
  {
    const unsigned short* px = Uxt;
    const unsigned short* pf = Uxt + 512;
    #pragma unroll
    for (int l = 0; l < 16; ++l) {
      xc[l] = *(const bf16x4*)px;
      fc[l] = *(const bf16x4*)pf;
      #pragma unroll
      for (int j = 0; j < 4; ++j) {
        float f  = bf2f((unsigned short)fc[l][j]);
        float xt = bf2f((unsigned short)xc[l][j]);
        c[j] = f * c[j] + (1.f - f) * xt;
        P[j] *= f;
      }
      px += N; pf += N;
    }
  }
  float* myP = &sP[ch * 36 + hv * 4];
  float* myQ = &sQ[ch * 36 + hv * 4];
  #pragma unroll
  for (int j = 0; j < 4; ++j) { myP[j] = P[j]; myQ[j] = c[j]; }
  __syncthreads();

  // Hillis-Steele inclusive affine scan over chunks.
  // Race-hardened: unconditional clamped-index read, then explicit lgkmcnt(0)
  // pin (+sched_barrier, rule #18) so reads provably complete before the
  // barrier that releases the partner's overwrite.
  for (int s = 1; s < 64; s <<= 1) {
    const int src = (ch >= s) ? (ch - s) : ch;
    float pp[4], pq[4];
    const float* qP = &sP[src * 36 + hv * 4];
    const float* qQ = &sQ[src * 36 + hv * 4];
    #pragma unroll
    for (int j = 0; j < 4; ++j) { pp[j] = qP[j]; pq[j] = qQ[j]; }
    asm volatile("s_waitcnt lgkmcnt(0)" ::: "memory");
    __builtin_amdgcn_sched_barrier(0);
    __syncthreads();
    if (ch >= s) {
      #pragma unroll
      for (int j = 0; j < 4; ++j) {
        c[j] = P[j] * pq[j] + c[j];
        P[j] = P[j] * pp[j];
        myP[j] = P[j]; myQ[j] = c[j];
      }
    }
    __syncthreads();
  }

  float cc[4];
  if (ch == 0) {
    #pragma unroll
    for (int j = 0; j < 4; ++j) cc[j] = 0.f;
  } else {
    const float* qQ = &sQ[(ch - 1) * 36 + hv * 4];
    #pragma unroll
    for (int j = 0; j < 4; ++j) cc[j] = qQ[j];
  }

  // pass 2: real scan + highway write (xt,f from registers)
  const unsigned short* pr = Uxt + 1024;
  const unsigned short* pxr = first ? (Uxt + 1536) : (hin + rowBase * 512 + h0);
  const int xr_stride = first ? N : 512;
  unsigned short* ob = hout_bf ? hout_bf + rowBase * 512 + h0 : (unsigned short*)nullptr;
  float* of = hout_f32 ? hout_f32 + rowBase * 512 + h0 : (float*)nullptr;
  #pragma unroll
  for (int l = 0; l < 16; ++l) {
    bf16x4 rv = *(const bf16x4*)pr;
    bf16x4 xrv = *(const bf16x4*)pxr;
    bf16x4 obuf;
    float ofl[4];
    #pragma unroll
    for (int j = 0; j < 4; ++j) {
      float f  = bf2f((unsigned short)fc[l][j]);
      float xt = bf2f((unsigned short)xc[l][j]);
      cc[j] = f * cc[j] + (1.f - f) * xt;
      float r  = bf2f((unsigned short)rv[j]);
      float xr = bf2f((unsigned short)xrv[j]);
      float o = r * cc[j] + (1.f - r) * xr;
      obuf[j] = (short)f2bf(o);
      ofl[j] = o;
    }
    if (ob) { *(bf16x4*)ob = obuf; ob += 512; }
    if (of) {
      *(float4*)of = make_float4(ofl[0], ofl[1], ofl[2], ofl[3]);
      of += 512;
    }
    pr += N; pxr += xr_stride;
  }
  if (ch == 63) {
    #pragma unroll
    for (int j = 0; j < 4; ++j) hidden[(size_t)b * 512 + h0 + j] = cc[j];
  }
}

// ---------- head ----------
__global__ __launch_bounds__(256)
void proj_kernel(const float* __restrict__ hfull, const float* __restrict__ Wp,
                 const float* __restrict__ bp, const float* __restrict__ Wc,
                 const float* __restrict__ bc, float* __restrict__ out) {
  __shared__ float hl[512];
  __shared__ float pr[512];
  const int b = blockIdx.x, t = threadIdx.x;
  const float* hrow = hfull + ((size_t)b * 1024 + 1023) * 512;
  hl[t] = hrow[t];
  hl[t + 256] = hrow[t + 256];
  __syncthreads();
  for (int j = t; j < 512; j += 256) {
    float s = 0.f;
    for (int k = 0; k < 512; ++k) s += hl[k] * Wp[(size_t)k * 512 + j];
    pr[j] = s + bp[j];
  }
  __syncthreads();
  if (t < 16) {
    float s = 0.f;
    for (int k = 0; k < 512; ++k) s += pr[k] * Wc[k * 16 + t];
    out[b * 16 + t] = s + bc[t];
  }
}

extern "C" void kernel_launch(void* const* d_in, const int* in_sizes, int n_in,
                              void* d_out, int out_size, void* d_ws, size_t ws_size,
                              hipStream_t stream) {
  const float* x  = (const float*)d_in[0];
  const float* W0 = (const float*)d_in[1];
  const float* b0 = (const float*)d_in[2];
  const float* W1 = (const float*)d_in[3];
  const float* b1 = (const float*)d_in[4];
  const float* W2 = (const float*)d_in[5];
  const float* b2 = (const float*)d_in[6];
  const float* W3 = (const float*)d_in[7];
  const float* b3 = (const float*)d_in[8];
  const float* Wp = (const float*)d_in[9];
  const float* bp = (const float*)d_in[10];
  const float* Wc = (const float*)d_in[11];
  const float* bc = (const float*)d_in[12];

  float* out = (float*)d_out;
  float* outO = out;                                   // (32,16)
  float* outH = out + 512;                             // (32,1024,512)
  float* outHid = out + 512 + (size_t)32 * 1024 * 512; // (4,32,512)

  char* ws = (char*)d_ws;
  size_t off = 0;
  auto alloc = [&](size_t bytes) {
    void* p = ws + off;
    off += (bytes + 255) & ~(size_t)255;
    return p;
  };
  unsigned short* Wt0 = (unsigned short*)alloc((size_t)2048 * 256 * 2);
  unsigned short* Wt1 = (unsigned short*)alloc((size_t)1536 * 512 * 2);
  unsigned short* Wt2 = (unsigned short*)alloc((size_t)1536 * 512 * 2);
  unsigned short* Wt3 = (unsigned short*)alloc((size_t)1536 * 512 * 2);
  unsigned short* xbf = (unsigned short*)alloc((size_t)32768 * 256 * 2);
  unsigned short* h0  = (unsigned short*)alloc((size_t)32768 * 512 * 2);
  unsigned short* h1  = (unsigned short*)alloc((size_t)32768 * 512 * 2);
  unsigned short* Ubf = (unsigned short*)alloc((size_t)32768 * 2048 * 2);
  (void)ws_size; (void)in_sizes; (void)n_in; (void)out_size;

  // fused prep: 8192 convert blocks + 512 + 3*768 transpose blocks
  prep_kernel<<<8192 + 512 + 3 * 768, 256, 0, stream>>>(
      x, xbf, W0, Wt0, W1, Wt1, W2, Wt2, W3, Wt3);

  // layer 0: K=256, N=2048 (xt | f | r | xres); 256 mtiles x 16 ntiles
  gemm_gate_kernel<<<256 * 16, 512, 0, stream>>>(xbf, Wt0, b0, Ubf, 2048, 256, 16);
  scan_kernel<<<512, 512, 0, stream>>>(Ubf, 2048, 1, nullptr, h0, nullptr, outHid + 0);
  // layer 1: 256 x 12
  gemm_gate_kernel<<<256 * 12, 512, 0, stream>>>(h0, Wt1, b1, Ubf, 1536, 512, 12);
  scan_kernel<<<512, 512, 0, stream>>>(Ubf, 1536, 0, h0, h1, nullptr, outHid + 16384);
  // layer 2
  gemm_gate_kernel<<<256 * 12, 512, 0, stream>>>(h1, Wt2, b2, Ubf, 1536, 512, 12);
  scan_kernel<<<512, 512, 0, stream>>>(Ubf, 1536, 0, h1, h0, nullptr, outHid + 32768);
  // layer 3: write final h as fp32 straight to d_out
  gemm_gate_kernel<<<256 * 12, 512, 0, stream>>>(h0, Wt3, b3, Ubf, 1536, 512, 12);
  scan_kernel<<<512, 512, 0, stream>>>(Ubf, 1536, 0, h0, nullptr, outH, outHid + 49152);

  proj_kernel<<<32, 256, 0, stream>>>(outH, Wp, bp, Wc, bc, outO);
}

// Round 16
// 513.622 us; speedup vs baseline: 1.3652x; 1.0566x over previous
//
#include <hip/hip_runtime.h>

#define DEV_INLINE __device__ __forceinline__

typedef __attribute__((ext_vector_type(8))) short bf16x8;
typedef __attribute__((ext_vector_type(4))) float f32x4;

// ---------- bf16 bit helpers ----------
DEV_INLINE unsigned short f2bf(float f) {
  union { float f; unsigned u; } v; v.f = f;
  unsigned r = v.u + 0x7FFFu + ((v.u >> 16) & 1u);  // round-to-nearest-even
  return (unsigned short)(r >> 16);
}
DEV_INLINE float bf2f(unsigned short u) {
  union { unsigned u; float f; } v; v.u = ((unsigned)u) << 16;
  return v.f;
}
DEV_INLINE float sigmoidf_(float x) { return 1.0f / (1.0f + __expf(-x)); }

DEV_INLINE void gload_lds16(const void* g, void* l) {
  __builtin_amdgcn_global_load_lds(
      (const __attribute__((address_space(1))) void*)(g),
      (__attribute__((address_space(3))) void*)(l), 16, 0, 0);
}

// ---------- fused prep: x fp32->bf16 (blocks 0..8191) + 4 weight transposes ----------
__global__ __launch_bounds__(256)
void prep_kernel(const float* __restrict__ x, unsigned short* __restrict__ xbf,
                 const float* __restrict__ W0, unsigned short* __restrict__ Wt0,
                 const float* __restrict__ W1, unsigned short* __restrict__ Wt1,
                 const float* __restrict__ W2, unsigned short* __restrict__ Wt2,
                 const float* __restrict__ W3, unsigned short* __restrict__ Wt3) {
  __shared__ float tile[32][33];
  const int id = blockIdx.x;
  const int t = threadIdx.x;
  if (id < 8192) {                      // x convert: 8192*256 float4 = 32768*256 floats
    const int i = id * 256 + t;
    const float4 v = reinterpret_cast<const float4*>(x)[i];
    ushort4 o;
    o.x = f2bf(v.x); o.y = f2bf(v.y); o.z = f2bf(v.z); o.w = f2bf(v.w);
    reinterpret_cast<ushort4*>(xbf)[i] = o;
    return;
  }
  int rid = id - 8192;
  const float* W; unsigned short* Wt; int K, N, bx, by;
  if (rid < 512) {                      // W0: [256][2048] -> [2048][256]
    W = W0; Wt = Wt0; K = 256; N = 2048; bx = rid & 7; by = rid >> 3;
  } else {                              // W1..W3: [512][1536] -> [1536][512]
    rid -= 512;
    const int seg = rid / 768; rid -= seg * 768;
    K = 512; N = 1536;
    W  = seg == 0 ? W1  : (seg == 1 ? W2  : W3);
    Wt = seg == 0 ? Wt1 : (seg == 1 ? Wt2 : Wt3);
    bx = rid & 15; by = rid >> 4;
  }
  const int tx = t & 31, ty = t >> 5;   // (32,8)
  const int kb = bx * 32, nb = by * 32;
  #pragma unroll
  for (int i = 0; i < 32; i += 8)
    tile[ty + i][tx] = W[(size_t)(kb + ty + i) * N + (nb + tx)];
  __syncthreads();
  #pragma unroll
  for (int i = 0; i < 32; i += 8)
    Wt[(size_t)(nb + ty + i) * K + (kb + tx)] = f2bf(tile[tx][ty + i]);
}

// ---------- GEMM + fused gate epilogue (R12-validated optimum) ----------
// Block tile 128(M) x 128(N), BK=64, 512 thr = 8 waves as 2M x 4N
// (wave-tile 64x32). Single-buffer: stage -> barrier -> compute -> barrier.
// LDS 32 KiB (A 16 + B 16).
// U[m][n] = gate_n( sum_k A[m][k]*Bt[n][k] )  stored bf16.
// regions (H=512): n>>9==1 -> sigmoid(v+bias[n&511]); ==2 -> sigmoid(v+bias[512+(n&511)]).
__global__ __launch_bounds__(512, 4)
void gemm_gate_kernel(const unsigned short* __restrict__ A,   // [M][K] bf16 bits
                      const unsigned short* __restrict__ Bt,  // [N][K] bf16 bits
                      const float* __restrict__ bias,         // [1024]
                      unsigned short* __restrict__ U,         // [M][N] bf16 bits
                      int N, int K, int NTN) {
  __shared__ short smem[2 * 128 * 64];   // As 16 KiB | Bs 16 KiB
  short* As = smem;
  short* Bs = smem + 128 * 64;

  const int tid = threadIdx.x;
  const int lane = tid & 63;
  const int l15 = lane & 15;
  const int l4 = lane >> 4;
  const int w = tid >> 6;          // 0..7
  const int wr = (w >> 2) * 64;    // wave M offset (0 or 64)
  const int wc = (w & 3) * 32;     // wave N offset (0,32,64,96)

  // XCD-aware bijective swizzle, then ntile-fast decomposition for L2 reuse.
  const int nwg = gridDim.x;            // multiple of 8
  const int cpx = nwg >> 3;
  const int swz = (blockIdx.x & 7) * cpx + (blockIdx.x >> 3);
  const int mtile = swz / NTN;
  const int ntile = swz - mtile * NTN;
  const int m0 = mtile * 128;
  const int n0 = ntile * 128;

  f32x4 acc[4][2];
  #pragma unroll
  for (int i = 0; i < 4; ++i)
    #pragma unroll
    for (int j = 0; j < 2; ++j)
      acc[i][j] = (f32x4){0.f, 0.f, 0.f, 0.f};

  const unsigned short* Abase = A + (size_t)m0 * K;
  const unsigned short* Bbase = Bt + (size_t)n0 * K;
  const int nsteps = K >> 6;

  for (int t = 0; t < nsteps; ++t) {
    const int k0 = t * 64;
    // stage A tile [128][64] and B tile [128][64], 2 chunks/thread each;
    // linear LDS dest, source k-slot pre-swizzled (involution sl ^ (row&7)).
    #pragma unroll
    for (int it = 0; it < 2; ++it) {
      int c = it * 512 + tid;
      int row = c >> 3, sl = c & 7;
      int ks = sl ^ (row & 7);
      gload_lds16(Abase + (size_t)row * K + (k0 + ks * 8), &As[c * 8]);
    }
    #pragma unroll
    for (int it = 0; it < 2; ++it) {
      int c = it * 512 + tid;
      int row = c >> 3, sl = c & 7;
      int ks = sl ^ (row & 7);
      gload_lds16(Bbase + (size_t)row * K + (k0 + ks * 8), &Bs[c * 8]);
    }
    __syncthreads();

    const bf16x8* As8 = (const bf16x8*)As;
    const bf16x8* Bs8 = (const bf16x8*)Bs;
    #pragma unroll
    for (int kk = 0; kk < 2; ++kk) {
      bf16x8 af[4], bfr[2];
      #pragma unroll
      for (int i = 0; i < 4; ++i) {
        int r = wr + i * 16 + l15;
        int phys = (kk * 4 + l4) ^ (r & 7);
        af[i] = As8[r * 8 + phys];
      }
      #pragma unroll
      for (int j = 0; j < 2; ++j) {
        int r = wc + j * 16 + l15;
        int phys = (kk * 4 + l4) ^ (r & 7);
        bfr[j] = Bs8[r * 8 + phys];
      }
      #pragma unroll
      for (int i = 0; i < 4; ++i)
        #pragma unroll
        for (int j = 0; j < 2; ++j)
          acc[i][j] = __builtin_amdgcn_mfma_f32_16x16x32_bf16(af[i], bfr[j], acc[i][j], 0, 0, 0);
    }
    __syncthreads();
  }

  // ---- epilogue: gate + direct bf16 stores (validated pattern) ----
  #pragma unroll
  for (int i = 0; i < 4; ++i) {
    const int grow0 = m0 + wr + i * 16 + l4 * 4;
    #pragma unroll
    for (int j = 0; j < 2; ++j) {
      const int gcol = n0 + wc + j * 16 + l15;
      const int region = gcol >> 9;
      const bool gate = (region == 1) | (region == 2);
      const float bval = (region == 1) ? bias[gcol & 511]
                       : ((region == 2) ? bias[512 + (gcol & 511)] : 0.f);
      #pragma unroll
      for (int reg = 0; reg < 4; ++reg) {
        float v = acc[i][j][reg];
        if (gate) v = sigmoidf_(v + bval);
        U[(size_t)(grow0 + reg) * N + gcol] = f2bf(v);
      }
    }
  }
}

// ---------- chunked linear-recurrence scan, vectorized 8 h / lane ----------
// grid: 32 b x 8 hslices = 256 blocks; block: 512 thr = 64 chunks(16 steps) x 8 hv
__global__ __launch_bounds__(512)
void scan_kernel(const unsigned short* __restrict__ U, int N, int first,
                 const unsigned short* __restrict__ hin,   // [M][512] bf16 (xres) if !first
                 unsigned short* __restrict__ hout_bf,     // [M][512] bf16 or null
                 float* __restrict__ hout_f32,             // [M][512] f32 or null
                 float* __restrict__ hidden) {             // [B][512]
  const int b = blockIdx.x >> 3;
  const int hslice = blockIdx.x & 7;
  const int hv = threadIdx.x & 7;
  const int ch = threadIdx.x >> 3;
  const int h0 = (hslice << 6) + (hv << 3);
  __shared__ float sP[64 * 68];
  __shared__ float sQ[64 * 68];

  const size_t rowBase = (size_t)b * 1024 + (size_t)ch * 16;
  const unsigned short* Uxt = U + rowBase * N + h0;

  // pass 1: chunk-local (P, Q) with c_in = 0
  float c[8], P[8];
  #pragma unroll
  for (int j = 0; j < 8; ++j) { c[j] = 0.f; P[j] = 1.f; }
  {
    const unsigned short* px = Uxt;
    const unsigned short* pf = Uxt + 512;
    #pragma unroll 2
    for (int l = 0; l < 16; ++l) {
      bf16x8 xv = *(const bf16x8*)px;
      bf16x8 fv = *(const bf16x8*)pf;
      #pragma unroll
      for (int j = 0; j < 8; ++j) {
        float f  = bf2f((unsigned short)fv[j]);
        float xt = bf2f((unsigned short)xv[j]);
        c[j] = f * c[j] + (1.f - f) * xt;
        P[j] *= f;
      }
      px += N; pf += N;
    }
  }
  float* myP = &sP[ch * 68 + hv * 8];
  float* myQ = &sQ[ch * 68 + hv * 8];
  #pragma unroll
  for (int j = 0; j < 8; ++j) { myP[j] = P[j]; myQ[j] = c[j]; }
  __syncthreads();

  // Hillis-Steele inclusive affine scan over chunks.
  // Race-hardened: unconditional clamped-index read, then explicit lgkmcnt(0)
  // pin (+sched_barrier, rule #18) so reads provably complete before the
  // barrier that releases the partner's overwrite.
  for (int s = 1; s < 64; s <<= 1) {
    const int src = (ch >= s) ? (ch - s) : ch;
    float pp[8], pq[8];
    const float* qP = &sP[src * 68 + hv * 8];
    const float* qQ = &sQ[src * 68 + hv * 8];
    #pragma unroll
    for (int j = 0; j < 8; ++j) { pp[j] = qP[j]; pq[j] = qQ[j]; }
    asm volatile("s_waitcnt lgkmcnt(0)" ::: "memory");
    __builtin_amdgcn_sched_barrier(0);
    __syncthreads();
    if (ch >= s) {
      #pragma unroll
      for (int j = 0; j < 8; ++j) {
        c[j] = P[j] * pq[j] + c[j];
        P[j] = P[j] * pp[j];
        myP[j] = P[j]; myQ[j] = c[j];
      }
    }
    __syncthreads();
  }

  float cc[8];
  if (ch == 0) {
    #pragma unroll
    for (int j = 0; j < 8; ++j) cc[j] = 0.f;
  } else {
    const float* qQ = &sQ[(ch - 1) * 68 + hv * 8];
    #pragma unroll
    for (int j = 0; j < 8; ++j) cc[j] = qQ[j];
  }

  // pass 2: real scan + highway write
  const unsigned short* px = Uxt;
  const unsigned short* pf = Uxt + 512;
  const unsigned short* pr = Uxt + 1024;
  const unsigned short* pxr = first ? (Uxt + 1536) : (hin + rowBase * 512 + h0);
  const int xr_stride = first ? N : 512;
  unsigned short* ob = hout_bf ? hout_bf + rowBase * 512 + h0 : (unsigned short*)nullptr;
  float* of = hout_f32 ? hout_f32 + rowBase * 512 + h0 : (float*)nullptr;
  #pragma unroll 2
  for (int l = 0; l < 16; ++l) {
    bf16x8 xv = *(const bf16x8*)px;
    bf16x8 fv = *(const bf16x8*)pf;
    bf16x8 rv = *(const bf16x8*)pr;
    bf16x8 xrv = *(const bf16x8*)pxr;
    bf16x8 obuf;
    float ofl[8];
    #pragma unroll
    for (int j = 0; j < 8; ++j) {
      float f  = bf2f((unsigned short)fv[j]);
      float xt = bf2f((unsigned short)xv[j]);
      cc[j] = f * cc[j] + (1.f - f) * xt;
      float r  = bf2f((unsigned short)rv[j]);
      float xr = bf2f((unsigned short)xrv[j]);
      float o = r * cc[j] + (1.f - r) * xr;
      obuf[j] = (short)f2bf(o);
      ofl[j] = o;
    }
    if (ob) { *(bf16x8*)ob = obuf; ob += 512; }
    if (of) {
      *(float4*)of = make_float4(ofl[0], ofl[1], ofl[2], ofl[3]);
      *(float4*)(of + 4) = make_float4(ofl[4], ofl[5], ofl[6], ofl[7]);
      of += 512;
    }
    px += N; pf += N; pr += N; pxr += xr_stride;
  }
  if (ch == 63) {
    #pragma unroll
    for (int j = 0; j < 8; ++j) hidden[(size_t)b * 512 + h0 + j] = cc[j];
  }
}

// ---------- head ----------
__global__ __launch_bounds__(256)
void proj_kernel(const float* __restrict__ hfull, const float* __restrict__ Wp,
                 const float* __restrict__ bp, const float* __restrict__ Wc,
                 const float* __restrict__ bc, float* __restrict__ out) {
  __shared__ float hl[512];
  __shared__ float pr[512];
  const int b = blockIdx.x, t = threadIdx.x;
  const float* hrow = hfull + ((size_t)b * 1024 + 1023) * 512;
  hl[t] = hrow[t];
  hl[t + 256] = hrow[t + 256];
  __syncthreads();
  for (int j = t; j < 512; j += 256) {
    float s = 0.f;
    for (int k = 0; k < 512; ++k) s += hl[k] * Wp[(size_t)k * 512 + j];
    pr[j] = s + bp[j];
  }
  __syncthreads();
  if (t < 16) {
    float s = 0.f;
    for (int k = 0; k < 512; ++k) s += pr[k] * Wc[k * 16 + t];
    out[b * 16 + t] = s + bc[t];
  }
}

extern "C" void kernel_launch(void* const* d_in, const int* in_sizes, int n_in,
                              void* d_out, int out_size, void* d_ws, size_t ws_size,
                              hipStream_t stream) {
  const float* x  = (const float*)d_in[0];
  const float* W0 = (const float*)d_in[1];
  const float* b0 = (const float*)d_in[2];
  const float* W1 = (const float*)d_in[3];
  const float* b1 = (const float*)d_in[4];
  const float* W2 = (const float*)d_in[5];
  const float* b2 = (const float*)d_in[6];
  const float* W3 = (const float*)d_in[7];
  const float* b3 = (const float*)d_in[8];
  const float* Wp = (const float*)d_in[9];
  const float* bp = (const float*)d_in[10];
  const float* Wc = (const float*)d_in[11];
  const float* bc = (const float*)d_in[12];

  float* out = (float*)d_out;
  float* outO = out;                                   // (32,16)
  float* outH = out + 512;                             // (32,1024,512)
  float* outHid = out + 512 + (size_t)32 * 1024 * 512; // (4,32,512)

  char* ws = (char*)d_ws;
  size_t off = 0;
  auto alloc = [&](size_t bytes) {
    void* p = ws + off;
    off += (bytes + 255) & ~(size_t)255;
    return p;
  };
  unsigned short* Wt0 = (unsigned short*)alloc((size_t)2048 * 256 * 2);
  unsigned short* Wt1 = (unsigned short*)alloc((size_t)1536 * 512 * 2);
  unsigned short* Wt2 = (unsigned short*)alloc((size_t)1536 * 512 * 2);
  unsigned short* Wt3 = (unsigned short*)alloc((size_t)1536 * 512 * 2);
  unsigned short* xbf = (unsigned short*)alloc((size_t)32768 * 256 * 2);
  unsigned short* h0  = (unsigned short*)alloc((size_t)32768 * 512 * 2);
  unsigned short* h1  = (unsigned short*)alloc((size_t)32768 * 512 * 2);
  unsigned short* Ubf = (unsigned short*)alloc((size_t)32768 * 2048 * 2);
  (void)ws_size; (void)in_sizes; (void)n_in; (void)out_size;

  // fused prep: 8192 convert blocks + 512 + 3*768 transpose blocks
  prep_kernel<<<8192 + 512 + 3 * 768, 256, 0, stream>>>(
      x, xbf, W0, Wt0, W1, Wt1, W2, Wt2, W3, Wt3);

  // layer 0: K=256, N=2048 (xt | f | r | xres); 256 mtiles x 16 ntiles
  gemm_gate_kernel<<<256 * 16, 512, 0, stream>>>(xbf, Wt0, b0, Ubf, 2048, 256, 16);
  scan_kernel<<<256, 512, 0, stream>>>(Ubf, 2048, 1, nullptr, h0, nullptr, outHid + 0);
  // layer 1: 256 x 12
  gemm_gate_kernel<<<256 * 12, 512, 0, stream>>>(h0, Wt1, b1, Ubf, 1536, 512, 12);
  scan_kernel<<<256, 512, 0, stream>>>(Ubf, 1536, 0, h0, h1, nullptr, outHid + 16384);
  // layer 2
  gemm_gate_kernel<<<256 * 12, 512, 0, stream>>>(h1, Wt2, b2, Ubf, 1536, 512, 12);
  scan_kernel<<<256, 512, 0, stream>>>(Ubf, 1536, 0, h1, h0, nullptr, outHid + 32768);
  // layer 3: write final h as fp32 straight to d_out
  gemm_gate_kernel<<<256 * 12, 512, 0, stream>>>(h0, Wt3, b3, Ubf, 1536, 512, 12);
  scan_kernel<<<256, 512, 0, stream>>>(Ubf, 1536, 0, h0, nullptr, outH, outHid + 49152);

  proj_kernel<<<32, 256, 0, stream>>>(outH, Wp, bp, Wc, bc, outO);
}